// Round 1
// 609.530 us; speedup vs baseline: 1.2527x; 1.2527x over previous
//
#include <hip/hip_runtime.h>
#include <hip/hip_bf16.h>

// GCN 3-layer: gcn_norm -> (GCNConv, ELU) x2 -> GCNConv
// N=100000, E=3200000, dims 128->32->64->128.
// agg is linear => aggregate in the SMALLER feature dim per layer:
//   L1: t1 = x@W1 (128->32); a1 = ELU(agg(t1) + b1)          [gather F=32]
//   L2: s2 = agg(a1);        h2 = ELU(s2@W2 + b2)            [gather F=32]
//   L3: s3 = agg(h2);        out = s3@W3 + b3                [gather F=64]
//
// CSR build (this round's rework): the old single-pass counting sort did
// 3.2M random 8B writes -> 200MB HBM write traffic (64B line allocated
// per edge, rocprof WRITE_SIZE) + 3.2M global cursor atomics + 3.2M
// packed deg atomics. Replaced with a bucketed 2-level sort:
//   1. k_hist:   bucket (=128 target nodes) histogram via LDS
//   2. k_bscan:  exclusive scan over 782 buckets
//   3. k_scatter:tile-local LDS histogram -> one run-reservation atomic
//                per (block,bucket), dense run writes into tmp[] (bucket-
//                sorted edges, 8B packed: r|c7<<17, w)
//   4. k_nodecnt:per-bucket LDS counters -> counts/offsets/dinv; NO
//                global atomics; deg uses same 2^24 fixed-point sum as
//                before (bit-identical dinv)
//   5. k_fill2:  per-bucket CSR fill; epk destination range is ~32KB
//                block-private -> dense L2-resident writes (~26MB total
//                vs 200MB amplified)
// tmp aliases bufA (first GEMM output) — both are exactly 25.6MB.
// GEMMs register-blocked 64-row tiles. Inputs: fp32 (probed vs bf16),
// edge_index i64 (probed vs i32). Output fp32.

constexpr int N = 100000;
constexpr int E = 3200000;

constexpr int BSHIFT = 7;
constexpr int BSIZE = 128;                       // nodes per bucket
constexpr int NBKT = (N + BSIZE - 1) / BSIZE;    // 782

constexpr float FIX_SCALE = 16777216.0f;         // 2^24

constexpr int HIST_EPB = 8192;                   // edges per block, hist
constexpr int SC_EPB = 16384;                    // edges per block, scatter

__device__ __forceinline__ float ldf(const void* p, int isbf, size_t i) {
    return isbf ? __bfloat162float(((const __hip_bfloat16*)p)[i])
                : ((const float*)p)[i];
}

__device__ __forceinline__ int ld_idx(const void* ei, int is64, size_t pos) {
    return is64 ? (int)((const long long*)ei)[pos] : ((const int*)ei)[pos];
}

// flags[0] = is64 (edge_index), flags[1] = isbf (float tensors)
// also zeroes the bucket-count array (runs before k_hist on the stream)
__global__ void k_probe(const void* ei, const void* x, int* flags, int* bkt_cnt) {
    __shared__ int bad64, bigcnt;
    int t = threadIdx.x;
    if (t == 0) { bad64 = 0; bigcnt = 0; }
    __syncthreads();
    long long v = ((const long long*)ei)[t];
    if (v < 0 || v >= (long long)N) atomicAdd(&bad64, 1);
    const unsigned short* u = (const unsigned short*)x;
    int big = 0;
    for (int i = t * 16; i < t * 16 + 16; i++) {
        int e = (u[i] >> 7) & 0xFF;
        if (e >= 133) big++;
    }
    atomicAdd(&bigcnt, big);
    for (int i = t; i < NBKT; i += 256) bkt_cnt[i] = 0;
    __syncthreads();
    if (t == 0) { flags[0] = (bad64 == 0) ? 1 : 0; flags[1] = (bigcnt < 40) ? 1 : 0; }
}

// bucket histogram: LDS per block, one global atomic per (block,bucket)
__global__ __launch_bounds__(256) void k_hist(const void* ei, const int* flags,
                                              int* bkt_cnt) {
    __shared__ int h[NBKT];
    int t = threadIdx.x;
    for (int i = t; i < NBKT; i += 256) h[i] = 0;
    __syncthreads();
    int is64 = flags[0];
    size_t eb = (size_t)blockIdx.x * HIST_EPB;
#pragma unroll 4
    for (int k = 0; k < HIST_EPB / 256; k++) {
        size_t e = eb + t + (size_t)k * 256;
        if (e < (size_t)E) {
            int c = ld_idx(ei, is64, (size_t)E + e);
            atomicAdd(&h[c >> BSHIFT], 1);
        }
    }
    __syncthreads();
    for (int i = t; i < NBKT; i += 256) {
        int v = h[i];
        if (v) atomicAdd(&bkt_cnt[i], v);
    }
}

// single-block exclusive scan over NBKT buckets -> bkt_off, bkt_cur
__global__ void k_bscan(const int* bkt_cnt, int* bkt_off, int* bkt_cur) {
    __shared__ int s[256];
    int t = threadIdx.x;
    int v[4]; int sum = 0;
#pragma unroll
    for (int j = 0; j < 4; j++) {
        int i = t * 4 + j;
        v[j] = (i < NBKT) ? bkt_cnt[i] : 0;
        sum += v[j];
    }
    s[t] = sum; __syncthreads();
    for (int st = 1; st < 256; st <<= 1) {
        int add = (t >= st) ? s[t - st] : 0;
        __syncthreads();
        s[t] += add;
        __syncthreads();
    }
    int excl = s[t] - sum;
#pragma unroll
    for (int j = 0; j < 4; j++) {
        int i = t * 4 + j;
        if (i < NBKT) { bkt_off[i] = excl; bkt_cur[i] = excl; excl += v[j]; }
    }
    if (t == 0) bkt_off[NBKT] = E;
}

// bucket-sort edges into tmp[]: per-block LDS histogram, one run
// reservation atomic per (block,bucket), dense run writes.
// tmp entry: .x = r | (c&127)<<17  (r<2^17, fits), .y = w bits
__global__ __launch_bounds__(256) void k_scatter(const void* ei, const int* flags,
                                                 const void* ew, int* bkt_cur,
                                                 int2* tmp) {
    __shared__ int h[NBKT];
    __shared__ int base_s[NBKT];
    int t = threadIdx.x;
    for (int i = t; i < NBKT; i += 256) h[i] = 0;
    __syncthreads();
    int is64 = flags[0], isbf = flags[1];
    size_t eb = (size_t)blockIdx.x * SC_EPB;
    int nb = (int)min((size_t)SC_EPB, (size_t)E - eb);
    // pass 1: local histogram
    for (int k = t; k < nb; k += 256) {
        int c = ld_idx(ei, is64, (size_t)E + eb + k);
        atomicAdd(&h[c >> BSHIFT], 1);
    }
    __syncthreads();
    // reserve a dense run per bucket
    for (int i = t; i < NBKT; i += 256) {
        int v = h[i];
        base_s[i] = v ? atomicAdd(&bkt_cur[i], v) : 0;
    }
    __syncthreads();
    for (int i = t; i < NBKT; i += 256) h[i] = 0;
    __syncthreads();
    // pass 2: place edges within reserved runs
    for (int k = t; k < nb; k += 256) {
        size_t e = eb + k;
        int r = ld_idx(ei, is64, e);
        int c = ld_idx(ei, is64, (size_t)E + e);
        float w = ldf(ew, isbf, e);
        int b = c >> BSHIFT;
        int loc = atomicAdd(&h[b], 1);
        int pos = base_s[b] + loc;
        tmp[pos] = make_int2(r | ((c & (BSIZE - 1)) << 17), __float_as_int(w));
    }
}

// per bucket: node counts + fixed-point weight sums (LDS atomics only),
// 128-wide LDS scan -> offsets; dinv = rsqrt(1 + wsum)  (bit-identical
// to the old packed-atomic scheme)
__global__ __launch_bounds__(256) void k_nodecnt(const int2* __restrict__ tmp,
                                                 const int* __restrict__ bkt_off,
                                                 int* __restrict__ counts,
                                                 int* __restrict__ offsets,
                                                 float* __restrict__ dinv) {
    __shared__ int cnt_s[BSIZE];
    __shared__ unsigned int wfx_s[BSIZE];
    __shared__ int sc_s[BSIZE];
    int t = threadIdx.x;
    int b = blockIdx.x;
    if (t < BSIZE) { cnt_s[t] = 0; wfx_s[t] = 0u; }
    __syncthreads();
    int s0 = bkt_off[b], s1 = bkt_off[b + 1];
    for (int p = s0 + t; p < s1; p += 256) {
        int2 ev = tmp[p];
        int c7 = (int)(((unsigned)ev.x) >> 17);
        float w = __int_as_float(ev.y);
        atomicAdd(&cnt_s[c7], 1);
        atomicAdd(&wfx_s[c7], (unsigned)__float2uint_rn(w * FIX_SCALE));
    }
    __syncthreads();
    if (t < BSIZE) sc_s[t] = cnt_s[t];
    __syncthreads();
    for (int st = 1; st < BSIZE; st <<= 1) {
        int add = (t < BSIZE && t >= st) ? sc_s[t - st] : 0;
        __syncthreads();
        if (t < BSIZE) sc_s[t] += add;
        __syncthreads();
    }
    if (t < BSIZE) {
        int node = b * BSIZE + t;
        if (node < N) {
            int c = cnt_s[t];
            offsets[node] = s0 + sc_s[t] - c;   // bucket base + exclusive
            counts[node] = c;
            float deg = 1.0f + (float)wfx_s[t] * (1.0f / FIX_SCALE);
            dinv[node] = rsqrtf(deg);
        }
    }
}

// per bucket: fill CSR epk[pos] = (src, dinv[src]*ew). Destination range
// is the bucket's contiguous ~32KB slice of epk -> block-private, dense.
__global__ __launch_bounds__(256) void k_fill2(const int2* __restrict__ tmp,
                                               const int* __restrict__ bkt_off,
                                               const int* __restrict__ offsets,
                                               const float* __restrict__ dinv,
                                               int2* __restrict__ epk) {
    __shared__ int lcur[BSIZE];
    int t = threadIdx.x;
    int b = blockIdx.x;
    if (t < BSIZE) {
        int node = b * BSIZE + t;
        lcur[t] = (node < N) ? offsets[node] : 0;
    }
    __syncthreads();
    int s0 = bkt_off[b], s1 = bkt_off[b + 1];
    for (int p = s0 + t; p < s1; p += 256) {
        int2 ev = tmp[p];
        unsigned px = (unsigned)ev.x;
        int r = (int)(px & 0x1FFFFu);
        int c7 = (int)(px >> 17);
        float w = __int_as_float(ev.y);
        float nr = dinv[r] * w;
        int pos = atomicAdd(&lcur[c7], 1);
        epk[pos] = make_int2(r, __float_as_int(nr));
    }
}

// --- register-blocked GEMM: H[N,FOUT] = X[N,FIN] @ W[FIN,FOUT] (+b, ELU)
template <int FIN, int FOUT, int TM, int TN, bool ADAPT, bool BIAS, bool ELU>
__global__ __launch_bounds__(256) void k_gemm(const void* __restrict__ X,
                                              const void* __restrict__ W,
                                              const void* __restrict__ bias,
                                              const int* __restrict__ flags,
                                              float* __restrict__ H) {
    constexpr int TCOLS = FOUT / TN;
    constexpr int TROWS = 256 / TCOLS;
    constexpr int BR = TROWS * TM;
    __shared__ float wl[FIN * FOUT];
    __shared__ float xt[FIN][BR + 1];
    int t = threadIdx.x;
    int isbf = flags[1];
    int base = blockIdx.x * BR;

    if (!isbf) {
        const float4* W4 = (const float4*)W;
        float4* wl4 = (float4*)wl;
        for (int i = t; i < FIN * FOUT / 4; i += 256) wl4[i] = W4[i];
    } else {
        for (int i = t; i < FIN * FOUT; i += 256)
            wl[i] = __bfloat162float(((const __hip_bfloat16*)W)[i]);
    }
    if (!ADAPT || !isbf) {
        const float4* X4 = (const float4*)X;
        for (int i = t; i < BR * FIN / 4; i += 256) {
            int row = i / (FIN / 4);
            int kq = i % (FIN / 4);
            int node = base + row;
            float4 v = make_float4(0.f, 0.f, 0.f, 0.f);
            if (node < N) v = X4[(size_t)node * (FIN / 4) + kq];
            int k = kq * 4;
            xt[k][row] = v.x; xt[k + 1][row] = v.y;
            xt[k + 2][row] = v.z; xt[k + 3][row] = v.w;
        }
    } else {
        for (int i = t; i < BR * FIN; i += 256) {
            int row = i / FIN, k = i % FIN;
            int node = base + row;
            float v = (node < N)
                ? __bfloat162float(((const __hip_bfloat16*)X)[(size_t)node * FIN + k]) : 0.f;
            xt[k][row] = v;
        }
    }
    __syncthreads();

    int tcol = t % TCOLS, trow = t / TCOLS;
    int r0 = trow * TM, c0 = tcol * TN;
    float acc[TM][TN] = {};
#pragma unroll 4
    for (int k = 0; k < FIN; k++) {
        float a[TM], b[TN];
#pragma unroll
        for (int m = 0; m < TM; m++) a[m] = xt[k][r0 + m];
#pragma unroll
        for (int n = 0; n < TN; n++) b[n] = wl[k * FOUT + c0 + n];
#pragma unroll
        for (int m = 0; m < TM; m++)
#pragma unroll
            for (int n = 0; n < TN; n++) acc[m][n] += a[m] * b[n];
    }
#pragma unroll
    for (int m = 0; m < TM; m++) {
        int node = base + r0 + m;
        if (node >= N) continue;
#pragma unroll
        for (int n = 0; n < TN; n++) {
            float v = acc[m][n];
            if (BIAS) v += ldf(bias, isbf, c0 + n);
            if (ELU) v = (v > 0.0f) ? v : expm1f(v);
            H[(size_t)node * FOUT + c0 + n] = v;
        }
    }
}

// --- aggregation: out[n] = di*Σ_e w'_e*H[src_e] + di^2*H[n] (+b, ELU)
// (w' = dinv[src]*ew stored in CSR; dinv[target]=di applied here once)
template <int F, bool BIAS, bool ELU>
__global__ __launch_bounds__(256) void k_agg(const float4* __restrict__ H4,
                                             const int* __restrict__ offsets,
                                             const int* __restrict__ counts,
                                             const int2* __restrict__ epk,
                                             const float* __restrict__ dinv,
                                             const void* __restrict__ bias,
                                             const int* __restrict__ flags,
                                             float4* __restrict__ out4) {
    constexpr int LPN = F / 4;        // lanes per node
    constexpr int NPB = 256 / LPN;    // nodes per block
    constexpr int STR = F / 4;        // float4 stride per row
    int t = threadIdx.x;
    int lane = t % LPN;
    int g = t / LPN;
    int node = blockIdx.x * NPB + g;
    if (node >= N) return;
    float di = dinv[node];
    float4 h = H4[(size_t)node * STR + lane];
    float4 acc = make_float4(0.f, 0.f, 0.f, 0.f);
    int p = offsets[node];
    int pend = p + counts[node];
    for (; p + 4 <= pend; p += 4) {
        int2 e0 = epk[p], e1 = epk[p + 1], e2 = epk[p + 2], e3 = epk[p + 3];
        float4 h0 = H4[(size_t)e0.x * STR + lane];
        float4 h1 = H4[(size_t)e1.x * STR + lane];
        float4 h2 = H4[(size_t)e2.x * STR + lane];
        float4 h3 = H4[(size_t)e3.x * STR + lane];
        float w0 = __int_as_float(e0.y), w1 = __int_as_float(e1.y);
        float w2 = __int_as_float(e2.y), w3 = __int_as_float(e3.y);
        acc.x += h0.x * w0 + h1.x * w1 + h2.x * w2 + h3.x * w3;
        acc.y += h0.y * w0 + h1.y * w1 + h2.y * w2 + h3.y * w3;
        acc.z += h0.z * w0 + h1.z * w1 + h2.z * w2 + h3.z * w3;
        acc.w += h0.w * w0 + h1.w * w1 + h2.w * w2 + h3.w * w3;
    }
    for (; p < pend; p++) {
        int2 e = epk[p];
        float4 hh = H4[(size_t)e.x * STR + lane];
        float w = __int_as_float(e.y);
        acc.x += hh.x * w; acc.y += hh.y * w; acc.z += hh.z * w; acc.w += hh.w * w;
    }
    float sw = di * di;
    acc.x = acc.x * di + h.x * sw;
    acc.y = acc.y * di + h.y * sw;
    acc.z = acc.z * di + h.z * sw;
    acc.w = acc.w * di + h.w * sw;
    if (BIAS) {
        int fb = lane * 4;
        int isbf = flags[1];
        acc.x += ldf(bias, isbf, fb);
        acc.y += ldf(bias, isbf, fb + 1);
        acc.z += ldf(bias, isbf, fb + 2);
        acc.w += ldf(bias, isbf, fb + 3);
    }
    if (ELU) {
        acc.x = (acc.x > 0.0f) ? acc.x : expm1f(acc.x);
        acc.y = (acc.y > 0.0f) ? acc.y : expm1f(acc.y);
        acc.z = (acc.z > 0.0f) ? acc.z : expm1f(acc.z);
        acc.w = (acc.w > 0.0f) ? acc.w : expm1f(acc.w);
    }
    out4[(size_t)node * STR + lane] = acc;
}

// diagnostic fallback: if ws_size too small, emit sentinel 123.0
__global__ void k_sentinel(float* out, int n) {
    int i = blockIdx.x * blockDim.x + threadIdx.x;
    if (i < n) out[i] = 123.0f;
}

extern "C" void kernel_launch(void* const* d_in, const int* in_sizes, int n_in,
                              void* d_out, int out_size, void* d_ws, size_t ws_size,
                              hipStream_t stream) {
    const void* x  = d_in[0];
    const void* ei = d_in[1];
    const void* ea = d_in[2];
    const void* W1 = d_in[3];
    const void* b1 = d_in[4];
    const void* W2 = d_in[5];
    const void* b2 = d_in[6];
    const void* W3 = d_in[7];
    const void* b3 = d_in[8];
    float* out = (float*)d_out;

    // workspace layout (256B aligned)
    char* ws = (char*)d_ws;
    size_t off = 0;
    auto alloc = [&](size_t bytes) {
        off = (off + 255) & ~(size_t)255;
        size_t r = off;
        off += bytes;
        return r;
    };
    float* dinv    = (float*)(ws + alloc((size_t)N * 4));
    int*   counts  = (int*)  (ws + alloc((size_t)N * 4));
    int*   offsets = (int*)  (ws + alloc((size_t)N * 4));
    int*   bkt_cnt = (int*)  (ws + alloc((size_t)NBKT * 4));
    int*   bkt_off = (int*)  (ws + alloc((size_t)(NBKT + 1) * 4));
    int*   bkt_cur = (int*)  (ws + alloc((size_t)NBKT * 4));
    int*   flags   = (int*)  (ws + alloc(256));
    int2*  epk     = (int2*) (ws + alloc((size_t)E * 8));
    float* bufA    = (float*)(ws + alloc((size_t)N * 64 * 4));
    float* bufB    = (float*)(ws + alloc((size_t)N * 64 * 4));
    size_t need = off;
    // tmp (bucket-sorted edges, E*8B = 25.6MB) aliases bufA (N*64*4 = 25.6MB):
    // tmp's last read (k_fill2) precedes bufA's first write (L1 GEMM).
    int2* tmp = (int2*)bufA;

    if (ws_size < need) {
        hipLaunchKernelGGL(k_sentinel, dim3((N * 128 + 255) / 256), dim3(256), 0, stream,
                           out, N * 128);
        return;
    }

    const int gH = (E + HIST_EPB - 1) / HIST_EPB;   // 391
    const int gS = (E + SC_EPB - 1) / SC_EPB;       // 196

    hipLaunchKernelGGL(k_probe, dim3(1), dim3(256), 0, stream, ei, x, flags, bkt_cnt);
    hipLaunchKernelGGL(k_hist, dim3(gH), dim3(256), 0, stream, ei, flags, bkt_cnt);
    hipLaunchKernelGGL(k_bscan, dim3(1), dim3(256), 0, stream, bkt_cnt, bkt_off, bkt_cur);
    hipLaunchKernelGGL(k_scatter, dim3(gS), dim3(256), 0, stream, ei, flags, ea, bkt_cur, tmp);
    hipLaunchKernelGGL(k_nodecnt, dim3(NBKT), dim3(256), 0, stream, tmp, bkt_off,
                       counts, offsets, dinv);
    hipLaunchKernelGGL(k_fill2, dim3(NBKT), dim3(256), 0, stream, tmp, bkt_off,
                       offsets, dinv, epk);

    // L1: t1 = x@W1 (bufA, F=32); a1 = ELU(agg(t1)+b1) (bufB)
    hipLaunchKernelGGL((k_gemm<128, 32, 2, 4, true, false, false>),
                       dim3((N + 63) / 64), dim3(256), 0, stream, x, W1, nullptr, flags, bufA);
    hipLaunchKernelGGL((k_agg<32, true, true>), dim3((N + 31) / 32), dim3(256), 0, stream,
                       (const float4*)bufA, offsets, counts, epk, dinv, b1, flags, (float4*)bufB);
    // L2: s2 = agg(a1) (bufA, F=32); h2 = ELU(s2@W2+b2) (bufB, F=64)
    hipLaunchKernelGGL((k_agg<32, false, false>), dim3((N + 31) / 32), dim3(256), 0, stream,
                       (const float4*)bufB, offsets, counts, epk, dinv, nullptr, flags, (float4*)bufA);
    hipLaunchKernelGGL((k_gemm<32, 64, 4, 4, false, true, true>),
                       dim3((N + 63) / 64), dim3(256), 0, stream, bufA, W2, b2, flags, bufB);
    // L3: s3 = agg(h2) (bufA, F=64); out = s3@W3+b3 (d_out, F=128)
    hipLaunchKernelGGL((k_agg<64, false, false>), dim3((N + 15) / 16), dim3(256), 0, stream,
                       (const float4*)bufB, offsets, counts, epk, dinv, nullptr, flags, (float4*)bufA);
    hipLaunchKernelGGL((k_gemm<64, 128, 4, 8, false, true, false>),
                       dim3((N + 63) / 64), dim3(256), 0, stream, bufA, W3, b3, flags, out);
}